// Round 2
// baseline (1828.052 us; speedup 1.0000x reference)
//
#include <hip/hip_runtime.h>
#include <hip/hip_bf16.h>
#include <math.h>

#define BB 8
#define CH 64
#define NP 4096
#define RG 32
#define R3 32768
#define LEAK 0.2f
#define BNEPS 1e-5f
#define GNEPS 1e-5f

// ---------------- voxelize stats: per-batch mean (3) + scale ----------------
__global__ void k_voxstats(const float* __restrict__ coords, float* __restrict__ ms){
  int b = blockIdx.x;
  __shared__ float red[256];
  float mean[3];
  for(int d=0; d<3; d++){
    float s=0.f;
    for(int i=threadIdx.x; i<NP; i+=256) s += coords[(b*3+d)*NP+i];
    red[threadIdx.x]=s; __syncthreads();
    for(int o=128;o>0;o>>=1){ if(threadIdx.x<o) red[threadIdx.x]+=red[threadIdx.x+o]; __syncthreads(); }
    mean[d]=red[0]/(float)NP; __syncthreads();
  }
  float mx=0.f;
  for(int i=threadIdx.x; i<NP; i+=256){
    float x=coords[(b*3+0)*NP+i]-mean[0];
    float y=coords[(b*3+1)*NP+i]-mean[1];
    float z=coords[(b*3+2)*NP+i]-mean[2];
    mx=fmaxf(mx, sqrtf(x*x+y*y+z*z));
  }
  red[threadIdx.x]=mx; __syncthreads();
  for(int o=128;o>0;o>>=1){ if(threadIdx.x<o) red[threadIdx.x]=fmaxf(red[threadIdx.x],red[threadIdx.x+o]); __syncthreads(); }
  if(threadIdx.x==0){
    ms[b*4+0]=mean[0]; ms[b*4+1]=mean[1]; ms[b*4+2]=mean[2];
    ms[b*4+3]=red[0]*2.0f;
  }
}

// ---------------- norm coords + voxel index ----------------
__global__ void k_assign(const float* __restrict__ coords, const float* __restrict__ ms,
                         float* __restrict__ nc, int* __restrict__ vi){
  int t = blockIdx.x*256+threadIdx.x;
  if(t>=BB*NP) return;
  int b=t/NP, n=t-b*NP;
  float scale=ms[b*4+3];
  int vox[3];
  #pragma unroll
  for(int d=0; d<3; d++){
    float c=coords[(b*3+d)*NP+n] - ms[b*4+d];
    float v=(c/scale + 0.5f)*32.0f;
    v=fminf(fmaxf(v,0.0f),31.0f);
    nc[(b*3+d)*NP+n]=v;
    vox[d]=(int)rintf(v);            // round half to even, matches jnp.round
  }
  vi[t]=vox[0]*1024+vox[1]*32+vox[2];
}

// ---------------- scatter features into voxel sums ----------------
__global__ void k_scatter(const float* __restrict__ feat, const int* __restrict__ vi,
                          float* __restrict__ gsum, float* __restrict__ cnt){
  int t = blockIdx.x*256+threadIdx.x;
  if(t>=BB*NP) return;
  int b=t/NP, n=t-b*NP;
  int idx=vi[t];
  atomicAdd(&cnt[b*R3+idx], 1.0f);
  for(int c=0;c<CH;c++)
    atomicAdd(&gsum[(size_t)(b*CH+c)*R3+idx], feat[(size_t)(b*CH+c)*NP+n]);
}

// ---------------- sums -> means ----------------
__global__ void k_gridmean(float* __restrict__ gsum, const float* __restrict__ cnt){
  int t=blockIdx.x*256+threadIdx.x;
  if(t>=BB*R3) return;
  float inv=1.0f/fmaxf(cnt[t],1.0f);
  int b=t/R3, v=t-b*R3;
  for(int c=0;c<CH;c++) gsum[(size_t)(b*CH+c)*R3+v]*=inv;
}

// ---------------- transpose conv weights to [cin][tap][oc] ----------------
__global__ void k_wt(const float* __restrict__ w, float* __restrict__ wt){
  int t=blockIdx.x*256+threadIdx.x;
  if(t>=CH*CH*27) return;
  int oc=t/(CH*27); int rem=t-oc*(CH*27); int ci=rem/27; int tap=rem-ci*27;
  wt[(ci*27+tap)*CH+oc]=w[t];
}

// ---------------- direct 3x3x3 conv + bias + BN + leaky ----------------
__global__ __launch_bounds__(256) void k_conv(const float* __restrict__ gin, float* __restrict__ gout,
    const float* __restrict__ wt, const float* __restrict__ bias,
    const float* __restrict__ bg, const float* __restrict__ bb,
    const float* __restrict__ bm, const float* __restrict__ bv){
  __shared__ float in_s[4][6][10][10];          // 9.6 KB
  __shared__ __align__(16) float w_s[4*27*64];  // 27.6 KB
  int blk=blockIdx.x;
  int b=blk>>7; int rem=blk&127;
  int tz=rem>>4, ty=(rem>>2)&3, tx=rem&3;
  int z0=tz*4, y0=ty*8, x0=tx*8;
  int tid=threadIdx.x;
  int s=tid&63, g=tid>>6;
  int ly=s>>3, lx=s&7;
  float acc[4][16];
  #pragma unroll
  for(int v=0;v<4;v++)
    #pragma unroll
    for(int j=0;j<16;j++) acc[v][j]=0.f;

  for(int chk=0; chk<16; chk++){
    int ci0=chk*4;
    __syncthreads();
    // stage input tile (6x10x10 x 4 cin) with zero pad
    for(int e=tid;e<2400;e+=256){
      int ci=e/600, r2=e-ci*600;
      int z=r2/100, rr=r2-z*100;
      int y=rr/10, x=rr-y*10;
      int gz=z0-1+z, gy=y0-1+y, gx=x0-1+x;
      float vv=0.f;
      if(((unsigned)gz<32u)&&((unsigned)gy<32u)&&((unsigned)gx<32u))
        vv=gin[(size_t)(b*CH+ci0+ci)*R3 + gz*1024+gy*32+gx];
      in_s[ci][z][y][x]=vv;
    }
    // stage weights (coalesced from pre-transposed wt)
    const float* wsrc=wt+(size_t)ci0*27*64;
    for(int e=tid;e<6912;e+=256) w_s[e]=wsrc[e];
    __syncthreads();

    for(int ci=0;ci<4;ci++){
      #pragma unroll
      for(int kz=0;kz<3;kz++){
        #pragma unroll
        for(int ky=0;ky<3;ky++){
          #pragma unroll
          for(int kx=0;kx<3;kx++){
            const float* wp=&w_s[((ci*27)+(kz*9+ky*3+kx))*64 + g*16];
            float wr[16] __attribute__((aligned(16)));
            #pragma unroll
            for(int q=0;q<4;q++) *(float4*)&wr[q*4]=((const float4*)wp)[q];
            #pragma unroll
            for(int v=0;v<4;v++){
              float xin=in_s[ci][v+kz][ly+ky][lx+kx];
              #pragma unroll
              for(int j=0;j<16;j++) acc[v][j]=fmaf(xin,wr[j],acc[v][j]);
            }
          }
        }
      }
    }
  }
  // epilogue: bias + BN + leaky
  #pragma unroll
  for(int j=0;j<16;j++){
    int oc=g*16+j;
    float iv=bg[oc]/sqrtf(bv[oc]+BNEPS);
    float sh=bb[oc]-bm[oc]*iv;
    float bs=bias[oc];
    #pragma unroll
    for(int v=0;v<4;v++){
      float yv=(acc[v][j]+bs)*iv+sh;
      yv = yv>=0.f ? yv : LEAK*yv;
      gout[(size_t)(b*CH+oc)*R3 + (z0+v)*1024 + (y0+ly)*32 + (x0+lx)] = yv;
    }
  }
}

// ---------------- point MLP: y = W @ feat + b ----------------
__global__ void k_ptgemm(const float* __restrict__ feat, const float* __restrict__ w,
                         const float* __restrict__ bias, float* __restrict__ y){
  __shared__ float ws_[64*64];
  int tid=threadIdx.x;
  for(int e=tid;e<4096;e+=256) ws_[e]=w[e];
  __syncthreads();
  int t=blockIdx.x*256+tid;
  if(t>=BB*NP) return;
  int b=t/NP, n=t-b*NP;
  float f[64];
  #pragma unroll 8
  for(int c=0;c<64;c++) f[c]=feat[(size_t)(b*CH+c)*NP+n];
  for(int o=0;o<64;o++){
    float sAcc=bias[o];
    #pragma unroll 8
    for(int c=0;c<64;c++) sAcc=fmaf(f[c], ws_[o*64+c], sAcc);
    y[(size_t)(b*CH+o)*NP+n]=sAcc;
  }
}

// ---------------- GroupNorm stats (8 groups x 8 ch x N) ----------------
__global__ void k_gnstats(const float* __restrict__ py, float* __restrict__ st){
  int b=blockIdx.x>>3, g=blockIdx.x&7;
  __shared__ float rs[256], rq[256];
  float s=0.f,q=0.f;
  for(int i=threadIdx.x;i<8*NP;i+=256){
    int cc=i>>12, n=i&4095;
    float v=py[(size_t)(b*CH+g*8+cc)*NP+n];
    s+=v; q+=v*v;
  }
  rs[threadIdx.x]=s; rq[threadIdx.x]=q;
  __syncthreads();
  for(int o=128;o>0;o>>=1){
    if(threadIdx.x<o){ rs[threadIdx.x]+=rs[threadIdx.x+o]; rq[threadIdx.x]+=rq[threadIdx.x+o]; }
    __syncthreads();
  }
  if(threadIdx.x==0){
    float mu=rs[0]/(8.f*NP);
    float var=rq[0]/(8.f*NP)-mu*mu;
    st[blockIdx.x*2+0]=mu;
    st[blockIdx.x*2+1]=1.0f/sqrtf(var+GNEPS);
  }
}

// ---------------- devoxelize + GN affine + swish + add ----------------
__global__ void k_fuse(const float* __restrict__ grid, const float* __restrict__ nc,
                       const float* __restrict__ py, const float* __restrict__ st,
                       const float* __restrict__ gg, const float* __restrict__ gb,
                       float* __restrict__ out){
  int t=blockIdx.x*256+threadIdx.x;
  if(t>=BB*NP) return;
  int b=t/NP, n=t-b*NP;
  float d_[3]; int i0[3], i1[3];
  #pragma unroll
  for(int dd=0;dd<3;dd++){
    float c=nc[(b*3+dd)*NP+n];
    c=fminf(fmaxf(c,0.f),31.f);
    float f=floorf(c);
    d_[dd]=c-f;
    i0[dd]=(int)f;
    i1[dd]=min(i0[dd]+1,31);
  }
  int idx8[8]; float w8[8];
  #pragma unroll
  for(int k=0;k<8;k++){
    int xx=(k&4)?i1[0]:i0[0];
    int yy=(k&2)?i1[1]:i0[1];
    int zz=(k&1)?i1[2]:i0[2];
    float wx=(k&4)?d_[0]:(1.f-d_[0]);
    float wy=(k&2)?d_[1]:(1.f-d_[1]);
    float wz=(k&1)?d_[2]:(1.f-d_[2]);
    idx8[k]=xx*1024+yy*32+zz;
    w8[k]=wx*wy*wz;
  }
  for(int c=0;c<CH;c++){
    const float* gp=grid+(size_t)(b*CH+c)*R3;
    float dv=0.f;
    #pragma unroll
    for(int k=0;k<8;k++) dv+=w8[k]*gp[idx8[k]];
    float mu  =st[(b*8+(c>>3))*2+0];
    float rstd=st[(b*8+(c>>3))*2+1];
    float yn=(py[(size_t)(b*CH+c)*NP+n]-mu)*rstd*gg[c]+gb[c];
    float sw=yn/(1.f+expf(-yn));
    out[(size_t)(b*CH+c)*NP+n]=dv+sw;
  }
}

// ---------------- passthrough copy ----------------
__global__ void k_copy(const float* __restrict__ src, float* __restrict__ dst, int n){
  int t=blockIdx.x*256+threadIdx.x;
  if(t<n) dst[t]=src[t];
}

extern "C" void kernel_launch(void* const* d_in, const int* in_sizes, int n_in,
                              void* d_out, int out_size, void* d_ws, size_t ws_size,
                              hipStream_t stream){
  const float* features=(const float*)d_in[0];
  const float* coords  =(const float*)d_in[1];
  const float* temb    =(const float*)d_in[2];
  const float* c1w=(const float*)d_in[3];
  const float* c1b=(const float*)d_in[4];
  const float* b1g=(const float*)d_in[5];
  const float* b1b=(const float*)d_in[6];
  const float* b1m=(const float*)d_in[7];
  const float* b1v=(const float*)d_in[8];
  const float* c2w=(const float*)d_in[9];
  const float* c2b=(const float*)d_in[10];
  const float* b2g=(const float*)d_in[11];
  const float* b2b=(const float*)d_in[12];
  const float* b2m=(const float*)d_in[13];
  const float* b2v=(const float*)d_in[14];
  const float* pfw=(const float*)d_in[15];
  const float* pfb=(const float*)d_in[16];
  const float* gng=(const float*)d_in[17];
  const float* gnb=(const float*)d_in[18];

  float* F=(float*)d_ws;
  float* ms  = F + 0;            // 32
  float* nc  = F + 32;           // 98304
  int*   vi  = (int*)(F + 98336);// 32768
  float* cnt = F + 131104;       // 262144
  float* w1t = F + 393248;       // 110592
  float* w2t = F + 503840;       // 110592
  float* py  = F + 614432;       // 2097152
  float* st  = F + 2711584;      // 128
  float* gA  = F + 2711712;      // 16777216
  float* gB  = F + 19488928;     // 16777216  (end: 36266144 floats ~ 145 MB)
  float* out=(float*)d_out;

  hipMemsetAsync(gA, 0, (size_t)16777216*4, stream);
  hipMemsetAsync(cnt,0, (size_t)262144*4, stream);

  k_voxstats<<<8,256,0,stream>>>(coords, ms);
  k_assign  <<<128,256,0,stream>>>(coords, ms, nc, vi);
  k_scatter <<<128,256,0,stream>>>(features, vi, gA, cnt);
  k_gridmean<<<1024,256,0,stream>>>(gA, cnt);
  k_wt      <<<432,256,0,stream>>>(c1w, w1t);
  k_wt      <<<432,256,0,stream>>>(c2w, w2t);
  k_conv    <<<1024,256,0,stream>>>(gA, gB, w1t, c1b, b1g, b1b, b1m, b1v);
  k_conv    <<<1024,256,0,stream>>>(gB, gA, w2t, c2b, b2g, b2b, b2m, b2v);
  k_ptgemm  <<<128,256,0,stream>>>(features, pfw, pfb, py);
  k_gnstats <<<64,256,0,stream>>>(py, st);
  k_fuse    <<<128,256,0,stream>>>(gA, nc, py, st, gng, gnb, out);
  k_copy    <<<(98304+255)/256,256,0,stream>>>(coords, out+2097152, 98304);
  k_copy    <<<2,256,0,stream>>>(temb, out+2195456, 512);
}

// Round 3
// 842.372 us; speedup vs baseline: 2.1701x; 2.1701x over previous
//
#include <hip/hip_runtime.h>
#include <hip/hip_bf16.h>
#include <math.h>

#define BB 8
#define CH 64
#define NP 4096
#define RG 32
#define R3 32768
#define LEAK 0.2f
#define BNEPS 1e-5f
#define GNEPS 1e-5f

typedef short short8 __attribute__((ext_vector_type(8)));
typedef float float4_ __attribute__((ext_vector_type(4)));

__device__ __forceinline__ short f2bf(float f){
  unsigned u = __float_as_uint(f);
  u += 0x7FFF + ((u>>16)&1);          // RNE
  return (short)(u>>16);
}

// ---------------- voxelize stats: per-batch mean (3) + scale ----------------
__global__ void k_voxstats(const float* __restrict__ coords, float* __restrict__ ms){
  int b = blockIdx.x;
  __shared__ float red[256];
  float mean[3];
  for(int d=0; d<3; d++){
    float s=0.f;
    for(int i=threadIdx.x; i<NP; i+=256) s += coords[(b*3+d)*NP+i];
    red[threadIdx.x]=s; __syncthreads();
    for(int o=128;o>0;o>>=1){ if(threadIdx.x<o) red[threadIdx.x]+=red[threadIdx.x+o]; __syncthreads(); }
    mean[d]=red[0]/(float)NP; __syncthreads();
  }
  float mx=0.f;
  for(int i=threadIdx.x; i<NP; i+=256){
    float x=coords[(b*3+0)*NP+i]-mean[0];
    float y=coords[(b*3+1)*NP+i]-mean[1];
    float z=coords[(b*3+2)*NP+i]-mean[2];
    mx=fmaxf(mx, sqrtf(x*x+y*y+z*z));
  }
  red[threadIdx.x]=mx; __syncthreads();
  for(int o=128;o>0;o>>=1){ if(threadIdx.x<o) red[threadIdx.x]=fmaxf(red[threadIdx.x],red[threadIdx.x+o]); __syncthreads(); }
  if(threadIdx.x==0){
    ms[b*4+0]=mean[0]; ms[b*4+1]=mean[1]; ms[b*4+2]=mean[2];
    ms[b*4+3]=red[0]*2.0f;
  }
}

// ---------------- norm coords + voxel index ----------------
__global__ void k_assign(const float* __restrict__ coords, const float* __restrict__ ms,
                         float* __restrict__ nc, int* __restrict__ vi){
  int t = blockIdx.x*256+threadIdx.x;
  if(t>=BB*NP) return;
  int b=t/NP, n=t-b*NP;
  float scale=ms[b*4+3];
  int vox[3];
  #pragma unroll
  for(int d=0; d<3; d++){
    float c=coords[(b*3+d)*NP+n] - ms[b*4+d];
    float v=(c/scale + 0.5f)*32.0f;
    v=fminf(fmaxf(v,0.0f),31.0f);
    nc[(b*3+d)*NP+n]=v;
    vox[d]=(int)rintf(v);            // round half to even, matches jnp.round
  }
  vi[t]=vox[0]*1024+vox[1]*32+vox[2];
}

// --------- scatter features into voxel sums ([b][vox][c] layout) ----------
__global__ void k_scatter(const float* __restrict__ feat, const int* __restrict__ vi,
                          float* __restrict__ gsum, float* __restrict__ cnt){
  int t = blockIdx.x*256+threadIdx.x;
  if(t>=BB*NP) return;
  int b=t/NP, n=t-b*NP;
  int idx=vi[t];
  atomicAdd(&cnt[b*R3+idx], 1.0f);
  float* gp = gsum + ((size_t)b*R3 + idx)*CH;
  for(int c=0;c<CH;c++)
    atomicAdd(&gp[c], feat[(size_t)(b*CH+c)*NP+n]);
}

// ---------------- sums -> means (float4 per thread) ----------------
__global__ void k_gridmean(float* __restrict__ gsum, const float* __restrict__ cnt){
  int t=blockIdx.x*256+threadIdx.x;
  if(t>=BB*R3*16) return;
  int v=t>>4, q=t&15;
  float inv=1.0f/fmaxf(cnt[v],1.0f);
  float4_* p=(float4_*)(gsum + (size_t)v*CH + q*4);
  float4_ x=*p;
  x[0]*=inv; x[1]*=inv; x[2]*=inv; x[3]*=inv;
  *p=x;
}

// ------- weights: w[oc][ci][tap] f32 -> wt2[tap][oc][ci] bf16 -------
__global__ void k_wt2(const float* __restrict__ w, short* __restrict__ wt2){
  int t=blockIdx.x*256+threadIdx.x;
  if(t>=CH*CH*27) return;
  int oc=t/(CH*27); int rem=t-oc*(CH*27); int ci=rem/27; int tap=rem-ci*27;
  wt2[(size_t)tap*CH*CH + oc*CH + ci]=f2bf(w[t]);
}

// ------------- MFMA implicit-GEMM 3x3x3 conv + bias + BN + leaky -------------
// gin/gout layout: [b][z][y][x][ci]  (ci innermost, 64)
__global__ __launch_bounds__(256,3) void k_conv_mfma(
    const float* __restrict__ gin, float* __restrict__ gout,
    const short* __restrict__ wt2, const float* __restrict__ bias,
    const float* __restrict__ bg, const float* __restrict__ bb,
    const float* __restrict__ bm, const float* __restrict__ bv){
  __shared__ __align__(16) short in_s[400*64];     // 51.2 KB, swizzled
  int tid=threadIdx.x;
  int blk=blockIdx.x;
  int b=blk>>8, zt=(blk>>4)&15, yt=(blk>>2)&3, xt=blk&3;
  int z0=zt*2, y0=yt*8, x0=xt*8;
  const float* gbase = gin + (size_t)b*R3*CH;

  // ---- stage input tile 4z x 10y x 10x, all 64 ci, f32->bf16, XOR-swizzled ----
  for(int idx=tid; idx<3200; idx+=256){
    int cb = idx/400, s = idx-cb*400;
    int z = s/100, r2=s-z*100, y=r2/10, x=r2-y*10;
    int gz=z0-1+z, gy=y0-1+y, gx=x0-1+x;
    short8 v = {0,0,0,0,0,0,0,0};
    if(((unsigned)gz<32u)&&((unsigned)gy<32u)&&((unsigned)gx<32u)){
      const float* src = gbase + ((size_t)(gz*1024+gy*32+gx))*CH + cb*8;
      #pragma unroll
      for(int j=0;j<8;j++) v[j]=f2bf(src[j]);
    }
    ((short8*)in_s)[s*8 + (cb ^ (s&7))] = v;
  }
  __syncthreads();

  int lane = tid&63, w = tid>>6;
  int zl = w>>1, h = w&1;            // wave: z-layer zl, row-half h
  int r15 = lane&15, g = lane>>4;
  int xx0 = r15&7, yb = h*4 + (r15>>3);   // y = yb + mf*2

  float4_ acc[2][4];
  #pragma unroll
  for(int mf=0;mf<2;mf++)
    #pragma unroll
    for(int nf=0;nf<4;nf++) acc[mf][nf]=(float4_){0.f,0.f,0.f,0.f};

  for(int kz=0;kz<3;kz++){
    for(int ky=0;ky<3;ky++){
      #pragma unroll
      for(int kx=0;kx<3;kx++){
        int tap=(kz*3+ky)*3+kx;
        const short8* wp = ((const short8*)wt2) + (size_t)tap*512;
        short8 bfrag[4][2];
        #pragma unroll
        for(int nf=0;nf<4;nf++)
          #pragma unroll
          for(int ks=0;ks<2;ks++)
            bfrag[nf][ks]=wp[(nf*16+r15)*8 + ks*4 + g];
        #pragma unroll
        for(int ks=0;ks<2;ks++){
          int cb = ks*4+g;
          #pragma unroll
          for(int mf=0;mf<2;mf++){
            int ss=(zl+kz)*100 + (yb+mf*2+ky)*10 + (xx0+kx);
            short8 a = ((const short8*)in_s)[ss*8 + (cb ^ (ss&7))];
            #pragma unroll
            for(int nf=0;nf<4;nf++)
              acc[mf][nf]=__builtin_amdgcn_mfma_f32_16x16x32_bf16(a, bfrag[nf][ks], acc[mf][nf],0,0,0);
          }
        }
      }
    }
  }

  // ---- epilogue: bias + BN + leaky, write [spatial][oc] ----
  float* gob = gout + ((size_t)b*R3 + (z0+zl)*1024)*CH;
  #pragma unroll
  for(int nf=0;nf<4;nf++){
    int oc=nf*16+r15;
    float iv=bg[oc]/sqrtf(bv[oc]+BNEPS);
    float sh=bias[oc]*iv + bb[oc]-bm[oc]*iv;
    #pragma unroll
    for(int mf=0;mf<2;mf++){
      #pragma unroll
      for(int q=0;q<4;q++){
        int row=h*32+mf*16+g*4+q;
        int yy=row>>3, xxo=row&7;
        float val=acc[mf][nf][q]*iv+sh;
        val = val>=0.f ? val : LEAK*val;
        gob[((size_t)((y0+yy)*32 + x0+xxo))*CH + oc]=val;
      }
    }
  }
}

// ---------------- point MLP: y = W @ feat + b ----------------
__global__ void k_ptgemm(const float* __restrict__ feat, const float* __restrict__ w,
                         const float* __restrict__ bias, float* __restrict__ y){
  __shared__ float ws_[64*64];
  int tid=threadIdx.x;
  for(int e=tid;e<4096;e+=256) ws_[e]=w[e];
  __syncthreads();
  int t=blockIdx.x*256+tid;
  if(t>=BB*NP) return;
  int b=t/NP, n=t-b*NP;
  float f[64];
  #pragma unroll 8
  for(int c=0;c<64;c++) f[c]=feat[(size_t)(b*CH+c)*NP+n];
  for(int o=0;o<64;o++){
    float sAcc=bias[o];
    #pragma unroll 8
    for(int c=0;c<64;c++) sAcc=fmaf(f[c], ws_[o*64+c], sAcc);
    y[(size_t)(b*CH+o)*NP+n]=sAcc;
  }
}

// ---------------- GroupNorm stats (8 groups x 8 ch x N) ----------------
__global__ void k_gnstats(const float* __restrict__ py, float* __restrict__ st){
  int b=blockIdx.x>>3, g=blockIdx.x&7;
  __shared__ float rs[256], rq[256];
  float s=0.f,q=0.f;
  for(int i=threadIdx.x;i<8*NP;i+=256){
    int cc=i>>12, n=i&4095;
    float v=py[(size_t)(b*CH+g*8+cc)*NP+n];
    s+=v; q+=v*v;
  }
  rs[threadIdx.x]=s; rq[threadIdx.x]=q;
  __syncthreads();
  for(int o=128;o>0;o>>=1){
    if(threadIdx.x<o){ rs[threadIdx.x]+=rs[threadIdx.x+o]; rq[threadIdx.x]+=rq[threadIdx.x+o]; }
    __syncthreads();
  }
  if(threadIdx.x==0){
    float mu=rs[0]/(8.f*NP);
    float var=rq[0]/(8.f*NP)-mu*mu;
    st[blockIdx.x*2+0]=mu;
    st[blockIdx.x*2+1]=1.0f/sqrtf(var+GNEPS);
  }
}

// ------- devoxelize (grid [b][vox][c]) + GN affine + swish + add -------
__global__ void k_fuse(const float* __restrict__ grid, const float* __restrict__ nc,
                       const float* __restrict__ py, const float* __restrict__ st,
                       const float* __restrict__ gg, const float* __restrict__ gb,
                       float* __restrict__ out){
  int t=blockIdx.x*256+threadIdx.x;
  if(t>=BB*NP) return;
  int b=t/NP, n=t-b*NP;
  float d_[3]; int i0[3], i1[3];
  #pragma unroll
  for(int dd=0;dd<3;dd++){
    float c=nc[(b*3+dd)*NP+n];
    c=fminf(fmaxf(c,0.f),31.f);
    float f=floorf(c);
    d_[dd]=c-f;
    i0[dd]=(int)f;
    i1[dd]=min(i0[dd]+1,31);
  }
  int idx8[8]; float w8[8];
  #pragma unroll
  for(int k=0;k<8;k++){
    int xx=(k&4)?i1[0]:i0[0];
    int yy=(k&2)?i1[1]:i0[1];
    int zz=(k&1)?i1[2]:i0[2];
    float wx=(k&4)?d_[0]:(1.f-d_[0]);
    float wy=(k&2)?d_[1]:(1.f-d_[1]);
    float wz=(k&1)?d_[2]:(1.f-d_[2]);
    idx8[k]=xx*1024+yy*32+zz;
    w8[k]=wx*wy*wz;
  }
  const float* gbase = grid + (size_t)b*R3*CH;
  for(int c=0;c<CH;c++){
    float dv=0.f;
    #pragma unroll
    for(int k=0;k<8;k++) dv+=w8[k]*gbase[(size_t)idx8[k]*CH + c];
    float mu  =st[(b*8+(c>>3))*2+0];
    float rstd=st[(b*8+(c>>3))*2+1];
    float yn=(py[(size_t)(b*CH+c)*NP+n]-mu)*rstd*gg[c]+gb[c];
    float sw=yn/(1.f+expf(-yn));
    out[(size_t)(b*CH+c)*NP+n]=dv+sw;
  }
}

// ---------------- passthrough copy ----------------
__global__ void k_copy(const float* __restrict__ src, float* __restrict__ dst, int n){
  int t=blockIdx.x*256+threadIdx.x;
  if(t<n) dst[t]=src[t];
}

extern "C" void kernel_launch(void* const* d_in, const int* in_sizes, int n_in,
                              void* d_out, int out_size, void* d_ws, size_t ws_size,
                              hipStream_t stream){
  const float* features=(const float*)d_in[0];
  const float* coords  =(const float*)d_in[1];
  const float* temb    =(const float*)d_in[2];
  const float* c1w=(const float*)d_in[3];
  const float* c1b=(const float*)d_in[4];
  const float* b1g=(const float*)d_in[5];
  const float* b1b=(const float*)d_in[6];
  const float* b1m=(const float*)d_in[7];
  const float* b1v=(const float*)d_in[8];
  const float* c2w=(const float*)d_in[9];
  const float* c2b=(const float*)d_in[10];
  const float* b2g=(const float*)d_in[11];
  const float* b2b=(const float*)d_in[12];
  const float* b2m=(const float*)d_in[13];
  const float* b2v=(const float*)d_in[14];
  const float* pfw=(const float*)d_in[15];
  const float* pfb=(const float*)d_in[16];
  const float* gng=(const float*)d_in[17];
  const float* gnb=(const float*)d_in[18];

  float* F=(float*)d_ws;
  float* ms  = F + 0;            // 32
  float* nc  = F + 32;           // 98304
  int*   vi  = (int*)(F + 98336);// 32768
  float* cnt = F + 131104;       // 262144
  short* w1t = (short*)(F + 393248);  // 110592 shorts (within 110592 floats)
  short* w2t = (short*)(F + 503840);
  float* py  = F + 614432;       // 2097152
  float* st  = F + 2711584;      // 128
  float* gA  = F + 2711712;      // 16777216
  float* gB  = F + 19488928;     // 16777216
  float* out=(float*)d_out;

  hipMemsetAsync(gA, 0, (size_t)16777216*4, stream);
  hipMemsetAsync(cnt,0, (size_t)262144*4, stream);

  k_voxstats<<<8,256,0,stream>>>(coords, ms);
  k_assign  <<<128,256,0,stream>>>(coords, ms, nc, vi);
  k_scatter <<<128,256,0,stream>>>(features, vi, gA, cnt);
  k_gridmean<<<16384,256,0,stream>>>(gA, cnt);
  k_wt2     <<<432,256,0,stream>>>(c1w, w1t);
  k_wt2     <<<432,256,0,stream>>>(c2w, w2t);
  k_conv_mfma<<<2048,256,0,stream>>>(gA, gB, w1t, c1b, b1g, b1b, b1m, b1v);
  k_conv_mfma<<<2048,256,0,stream>>>(gB, gA, w2t, c2b, b2g, b2b, b2m, b2v);
  k_ptgemm  <<<128,256,0,stream>>>(features, pfw, pfb, py);
  k_gnstats <<<64,256,0,stream>>>(py, st);
  k_fuse    <<<128,256,0,stream>>>(gA, nc, py, st, gng, gnb, out);
  k_copy    <<<(98304+255)/256,256,0,stream>>>(coords, out+2097152, 98304);
  k_copy    <<<2,256,0,stream>>>(temb, out+2195456, 512);
}

// Round 4
// 755.291 us; speedup vs baseline: 2.4203x; 1.1153x over previous
//
#include <hip/hip_runtime.h>
#include <hip/hip_bf16.h>
#include <math.h>

#define BB 8
#define CH 64
#define NP 4096
#define RG 32
#define R3 32768
#define LEAK 0.2f
#define BNEPS 1e-5f
#define GNEPS 1e-5f

typedef short short8 __attribute__((ext_vector_type(8)));
typedef float float4_ __attribute__((ext_vector_type(4)));

__device__ __forceinline__ short f2bf(float f){
  unsigned u = __float_as_uint(f);
  u += 0x7FFF + ((u>>16)&1);          // RNE
  return (short)(u>>16);
}
__device__ __forceinline__ float bf2f(short s){
  unsigned u = ((unsigned)(unsigned short)s)<<16;
  return __uint_as_float(u);
}

// ---------------- voxelize stats: per-batch mean (3) + scale ----------------
__global__ void k_voxstats(const float* __restrict__ coords, float* __restrict__ ms){
  int b = blockIdx.x;
  __shared__ float red[256];
  float mean[3];
  for(int d=0; d<3; d++){
    float s=0.f;
    for(int i=threadIdx.x; i<NP; i+=256) s += coords[(b*3+d)*NP+i];
    red[threadIdx.x]=s; __syncthreads();
    for(int o=128;o>0;o>>=1){ if(threadIdx.x<o) red[threadIdx.x]+=red[threadIdx.x+o]; __syncthreads(); }
    mean[d]=red[0]/(float)NP; __syncthreads();
  }
  float mx=0.f;
  for(int i=threadIdx.x; i<NP; i+=256){
    float x=coords[(b*3+0)*NP+i]-mean[0];
    float y=coords[(b*3+1)*NP+i]-mean[1];
    float z=coords[(b*3+2)*NP+i]-mean[2];
    mx=fmaxf(mx, sqrtf(x*x+y*y+z*z));
  }
  red[threadIdx.x]=mx; __syncthreads();
  for(int o=128;o>0;o>>=1){ if(threadIdx.x<o) red[threadIdx.x]=fmaxf(red[threadIdx.x],red[threadIdx.x+o]); __syncthreads(); }
  if(threadIdx.x==0){
    ms[b*4+0]=mean[0]; ms[b*4+1]=mean[1]; ms[b*4+2]=mean[2];
    ms[b*4+3]=red[0]*2.0f;
  }
}

// ---------------- norm coords + voxel index ----------------
__global__ void k_assign(const float* __restrict__ coords, const float* __restrict__ ms,
                         float* __restrict__ nc, int* __restrict__ vi){
  int t = blockIdx.x*256+threadIdx.x;
  if(t>=BB*NP) return;
  int b=t/NP, n=t-b*NP;
  float scale=ms[b*4+3];
  int vox[3];
  #pragma unroll
  for(int d=0; d<3; d++){
    float c=coords[(b*3+d)*NP+n] - ms[b*4+d];
    float v=(c/scale + 0.5f)*32.0f;
    v=fminf(fmaxf(v,0.0f),31.0f);
    nc[(b*3+d)*NP+n]=v;
    vox[d]=(int)rintf(v);            // round half to even, matches jnp.round
  }
  vi[t]=vox[0]*1024+vox[1]*32+vox[2];
}

// --------- scatter features into voxel sums ([b][vox][c]), 4 thr/point ----------
__global__ void k_scatter(const float* __restrict__ feat, const int* __restrict__ vi,
                          float* __restrict__ gsum, float* __restrict__ cnt){
  int t = blockIdx.x*256+threadIdx.x;
  if(t>=BB*NP*4) return;
  int p=t>>2, qq=t&3;
  int b=p/NP, n=p-b*NP;
  int idx=vi[p];
  if(qq==0) atomicAdd(&cnt[b*R3+idx], 1.0f);
  float* gp = gsum + ((size_t)b*R3 + idx)*CH + qq*16;
  const float* fp = feat + (size_t)b*CH*NP + n;
  #pragma unroll
  for(int c=0;c<16;c++)
    atomicAdd(&gp[c], fp[(size_t)(qq*16+c)*NP]);
}

// ---------------- sums -> means, f32 -> bf16 grid ----------------
__global__ void k_gridmean(const float* __restrict__ gsum, const float* __restrict__ cnt,
                           short* __restrict__ gbf){
  int t=blockIdx.x*256+threadIdx.x;
  if(t>=BB*R3*8) return;
  int v=t>>3, q=t&7;
  float inv=1.0f/fmaxf(cnt[v],1.0f);
  const float* sp=gsum + (size_t)v*CH + q*8;
  short8 o;
  #pragma unroll
  for(int j=0;j<8;j++) o[j]=f2bf(sp[j]*inv);
  ((short8*)gbf)[(size_t)v*8+q]=o;
}

// ------- weights: w[oc][ci][tap] f32 -> wt2[tap][oc][ci] bf16 -------
__global__ void k_wt2(const float* __restrict__ w, short* __restrict__ wt2){
  int t=blockIdx.x*256+threadIdx.x;
  if(t>=CH*CH*27) return;
  int oc=t/(CH*27); int rem=t-oc*(CH*27); int ci=rem/27; int tap=rem-ci*27;
  wt2[(size_t)tap*CH*CH + oc*CH + ci]=f2bf(w[t]);
}

// ------------- MFMA implicit-GEMM 3x3x3 conv + bias + BN + leaky -------------
// gin layout: [b][vox][ci] bf16; gout: [b][vox][oc] bf16
// tile 4z x 8y x 8x, 8 waves (zl = w>>1, h = w&1), ci in 2 halves of 32
__global__ __launch_bounds__(512,4) void k_conv_mfma(
    const short* __restrict__ gin, short* __restrict__ gout,
    const short* __restrict__ wt2, const float* __restrict__ bias,
    const float* __restrict__ bg, const float* __restrict__ bb,
    const float* __restrict__ bm, const float* __restrict__ bv){
  __shared__ __align__(16) short in_s[4*601*8];   // 4 ci-chunks x 601 slots x short8 = 38464 B
  int tid=threadIdx.x;
  int blk=blockIdx.x;                 // 8b x 8zt x 4yt x 4xt = 1024
  int b=blk>>7, zt=(blk>>4)&7, yt=(blk>>2)&3, xt=blk&3;
  int z0=zt*4, y0=yt*8, x0=xt*8;
  const short* gbase = gin + (size_t)b*R3*CH;

  int lane=tid&63, w=tid>>6;
  int zl=w>>1, h=w&1;
  int r15=lane&15, g=lane>>4;
  int ix=r15&7, iyb=h*4+(r15>>3);

  float4_ acc[2][4];
  #pragma unroll
  for(int mf=0;mf<2;mf++)
    #pragma unroll
    for(int nf=0;nf<4;nf++) acc[mf][nf]=(float4_){0.f,0.f,0.f,0.f};

  const short8* wt8=(const short8*)wt2;

  for(int hh=0; hh<2; hh++){
    __syncthreads();
    // stage input tile 6z x 10y x 10x, ci half hh (32 ch), bf16 straight copy
    for(int e=tid; e<2400; e+=512){
      int ss=e>>2, cb=e&3;
      int z=ss/100, r2=ss-z*100, y=r2/10, x=r2-y*10;
      int gz=z0-1+z, gy=y0-1+y, gx=x0-1+x;
      short8 v={0,0,0,0,0,0,0,0};
      if(((unsigned)gz<32u)&&((unsigned)gy<32u)&&((unsigned)gx<32u))
        v=*(const short8*)(gbase + ((gz<<10)+(gy<<5)+gx)*CH + hh*32 + cb*8);
      ((short8*)in_s)[cb*601+ss]=v;
    }
    __syncthreads();

    int woff = r15*8 + hh*4 + g;      // + nf*128 per oc-frag, + tap*512
    short8 bA[4], bB[4];
    #pragma unroll
    for(int nf=0;nf<4;nf++) bA[nf]=wt8[woff + nf*128];
    #pragma unroll
    for(int nf=0;nf<4;nf++) bB[nf]=wt8[512 + woff + nf*128];

    for(int tt=0; tt<27; tt+=2){
      {
        int kz=tt/9, r=tt-kz*9, ky=r/3, kx=r-ky*3;
        #pragma unroll
        for(int mf=0;mf<2;mf++){
          int ss=(zl+kz)*100+(iyb+mf*2+ky)*10+ix+kx;
          short8 a=((short8*)in_s)[g*601+ss];
          #pragma unroll
          for(int nf=0;nf<4;nf++)
            acc[mf][nf]=__builtin_amdgcn_mfma_f32_16x16x32_bf16(a,bA[nf],acc[mf][nf],0,0,0);
        }
        if(tt+2<27){
          #pragma unroll
          for(int nf=0;nf<4;nf++) bA[nf]=wt8[(tt+2)*512 + woff + nf*128];
        }
      }
      if(tt+1<27){
        int t1=tt+1;
        int kz=t1/9, r=t1-kz*9, ky=r/3, kx=r-ky*3;
        #pragma unroll
        for(int mf=0;mf<2;mf++){
          int ss=(zl+kz)*100+(iyb+mf*2+ky)*10+ix+kx;
          short8 a=((short8*)in_s)[g*601+ss];
          #pragma unroll
          for(int nf=0;nf<4;nf++)
            acc[mf][nf]=__builtin_amdgcn_mfma_f32_16x16x32_bf16(a,bB[nf],acc[mf][nf],0,0,0);
        }
        if(tt+3<27){
          #pragma unroll
          for(int nf=0;nf<4;nf++) bB[nf]=wt8[(tt+3)*512 + woff + nf*128];
        }
      }
    }
  }

  // ---- epilogue: bias + BN + leaky, bf16 out [vox][oc] ----
  short* go = gout + ((size_t)b*R3 + (size_t)(z0+zl)*1024)*CH;
  #pragma unroll
  for(int nf=0;nf<4;nf++){
    int oc=nf*16+r15;
    float iv=bg[oc]/sqrtf(bv[oc]+BNEPS);
    float sh=bias[oc]*iv + bb[oc]-bm[oc]*iv;
    #pragma unroll
    for(int mf=0;mf<2;mf++){
      #pragma unroll
      for(int q=0;q<4;q++){
        int row=h*32+mf*16+g*4+q;
        float val=acc[mf][nf][q]*iv+sh;
        val = val>=0.f ? val : LEAK*val;
        go[(size_t)((y0+(row>>3))*32 + x0+(row&7))*CH + oc]=f2bf(val);
      }
    }
  }
}

// ---------------- point MLP: y = W @ feat + b ----------------
__global__ void k_ptgemm(const float* __restrict__ feat, const float* __restrict__ w,
                         const float* __restrict__ bias, float* __restrict__ y){
  __shared__ float ws_[64*64];
  int tid=threadIdx.x;
  for(int e=tid;e<4096;e+=256) ws_[e]=w[e];
  __syncthreads();
  int t=blockIdx.x*256+tid;
  if(t>=BB*NP) return;
  int b=t/NP, n=t-b*NP;
  float f[64];
  #pragma unroll 8
  for(int c=0;c<64;c++) f[c]=feat[(size_t)(b*CH+c)*NP+n];
  for(int o=0;o<64;o++){
    float sAcc=bias[o];
    #pragma unroll 8
    for(int c=0;c<64;c++) sAcc=fmaf(f[c], ws_[o*64+c], sAcc);
    y[(size_t)(b*CH+o)*NP+n]=sAcc;
  }
}

// ---------------- GroupNorm stats (8 groups x 8 ch x N) ----------------
__global__ void k_gnstats(const float* __restrict__ py, float* __restrict__ st){
  int b=blockIdx.x>>3, g=blockIdx.x&7;
  __shared__ float rs[256], rq[256];
  float s=0.f,q=0.f;
  for(int i=threadIdx.x;i<8*NP;i+=256){
    int cc=i>>12, n=i&4095;
    float v=py[(size_t)(b*CH+g*8+cc)*NP+n];
    s+=v; q+=v*v;
  }
  rs[threadIdx.x]=s; rq[threadIdx.x]=q;
  __syncthreads();
  for(int o=128;o>0;o>>=1){
    if(threadIdx.x<o){ rs[threadIdx.x]+=rs[threadIdx.x+o]; rq[threadIdx.x]+=rq[threadIdx.x+o]; }
    __syncthreads();
  }
  if(threadIdx.x==0){
    float mu=rs[0]/(8.f*NP);
    float var=rq[0]/(8.f*NP)-mu*mu;
    st[blockIdx.x*2+0]=mu;
    st[blockIdx.x*2+1]=1.0f/sqrtf(var+GNEPS);
  }
}

// ------- devoxelize (bf16 grid [b][vox][c]) + GN affine + swish + add -------
// 4 threads per point, 16 channels each, short8 vector gathers
__global__ void k_fuse(const short* __restrict__ grid, const float* __restrict__ nc,
                       const float* __restrict__ py, const float* __restrict__ st,
                       const float* __restrict__ gg, const float* __restrict__ gb,
                       float* __restrict__ out){
  int t=blockIdx.x*256+threadIdx.x;
  if(t>=BB*NP*4) return;
  int p=t>>2, qq=t&3;
  int b=p/NP, n=p-b*NP;
  float d_[3]; int i0[3], i1[3];
  #pragma unroll
  for(int dd=0;dd<3;dd++){
    float c=nc[(b*3+dd)*NP+n];
    c=fminf(fmaxf(c,0.f),31.f);
    float f=floorf(c);
    d_[dd]=c-f;
    i0[dd]=(int)f;
    i1[dd]=min(i0[dd]+1,31);
  }
  int idx8[8]; float w8[8];
  #pragma unroll
  for(int k=0;k<8;k++){
    int xx=(k&4)?i1[0]:i0[0];
    int yy=(k&2)?i1[1]:i0[1];
    int zz=(k&1)?i1[2]:i0[2];
    float wx=(k&4)?d_[0]:(1.f-d_[0]);
    float wy=(k&2)?d_[1]:(1.f-d_[1]);
    float wz=(k&1)?d_[2]:(1.f-d_[2]);
    idx8[k]=xx*1024+yy*32+zz;
    w8[k]=wx*wy*wz;
  }
  const short* gbase = grid + (size_t)b*R3*CH;
  #pragma unroll
  for(int c8=0;c8<2;c8++){
    int c0=qq*16+c8*8;
    float dv[8]={0.f,0.f,0.f,0.f,0.f,0.f,0.f,0.f};
    #pragma unroll
    for(int k=0;k<8;k++){
      short8 gv=*(const short8*)(gbase + (size_t)idx8[k]*CH + c0);
      #pragma unroll
      for(int j=0;j<8;j++) dv[j]+=w8[k]*bf2f(gv[j]);
    }
    #pragma unroll
    for(int j=0;j<8;j++){
      int c=c0+j;
      float mu  =st[(b*8+(c>>3))*2+0];
      float rstd=st[(b*8+(c>>3))*2+1];
      float yn=(py[(size_t)(b*CH+c)*NP+n]-mu)*rstd*gg[c]+gb[c];
      float sw=yn/(1.f+expf(-yn));
      out[(size_t)(b*CH+c)*NP+n]=dv[j]+sw;
    }
  }
}

// ---------------- passthrough copy ----------------
__global__ void k_copy(const float* __restrict__ src, float* __restrict__ dst, int n){
  int t=blockIdx.x*256+threadIdx.x;
  if(t<n) dst[t]=src[t];
}

extern "C" void kernel_launch(void* const* d_in, const int* in_sizes, int n_in,
                              void* d_out, int out_size, void* d_ws, size_t ws_size,
                              hipStream_t stream){
  const float* features=(const float*)d_in[0];
  const float* coords  =(const float*)d_in[1];
  const float* temb    =(const float*)d_in[2];
  const float* c1w=(const float*)d_in[3];
  const float* c1b=(const float*)d_in[4];
  const float* b1g=(const float*)d_in[5];
  const float* b1b=(const float*)d_in[6];
  const float* b1m=(const float*)d_in[7];
  const float* b1v=(const float*)d_in[8];
  const float* c2w=(const float*)d_in[9];
  const float* c2b=(const float*)d_in[10];
  const float* b2g=(const float*)d_in[11];
  const float* b2b=(const float*)d_in[12];
  const float* b2m=(const float*)d_in[13];
  const float* b2v=(const float*)d_in[14];
  const float* pfw=(const float*)d_in[15];
  const float* pfb=(const float*)d_in[16];
  const float* gng=(const float*)d_in[17];
  const float* gnb=(const float*)d_in[18];

  float* F=(float*)d_ws;
  float* ms  = F + 0;              // 32
  float* nc  = F + 32;             // 98304
  int*   vi  = (int*)(F + 98336);  // 32768
  float* cnt = F + 131104;         // 262144
  short* w1t = (short*)(F + 393248);   // 110592 shorts = 55296 f
  short* w2t = (short*)(F + 448544);   // 55296 f
  float* py  = F + 503840;         // 2097152
  float* st  = F + 2600992;        // 128
  float* gA  = F + 2601120;        // 16777216 f32 (scatter sums)
  short* gBF1= (short*)(F + 19378336); // 16777216 shorts = 8388608 f (grid / conv2 out)
  short* gBF2= (short*)(F + 27766944); // conv1 out
  float* out=(float*)d_out;

  hipMemsetAsync(gA, 0, (size_t)16777216*4, stream);
  hipMemsetAsync(cnt,0, (size_t)262144*4, stream);

  k_voxstats<<<8,256,0,stream>>>(coords, ms);
  k_assign  <<<128,256,0,stream>>>(coords, ms, nc, vi);
  k_scatter <<<512,256,0,stream>>>(features, vi, gA, cnt);
  k_gridmean<<<8192,256,0,stream>>>(gA, cnt, gBF1);
  k_wt2     <<<432,256,0,stream>>>(c1w, w1t);
  k_wt2     <<<432,256,0,stream>>>(c2w, w2t);
  k_conv_mfma<<<1024,512,0,stream>>>(gBF1, gBF2, w1t, c1b, b1g, b1b, b1m, b1v);
  k_conv_mfma<<<1024,512,0,stream>>>(gBF2, gBF1, w2t, c2b, b2g, b2b, b2m, b2v);
  k_ptgemm  <<<128,256,0,stream>>>(features, pfw, pfb, py);
  k_gnstats <<<64,256,0,stream>>>(py, st);
  k_fuse    <<<512,256,0,stream>>>(gBF1, nc, py, st, gng, gnb, out);
  k_copy    <<<(98304+255)/256,256,0,stream>>>(coords, out+2097152, 98304);
  k_copy    <<<2,256,0,stream>>>(temb, out+2195456, 512);
}

// Round 5
// 358.942 us; speedup vs baseline: 5.0929x; 2.1042x over previous
//
#include <hip/hip_runtime.h>
#include <hip/hip_bf16.h>
#include <math.h>

#define BB 8
#define CH 64
#define NP 4096
#define RG 32
#define R3 32768
#define LEAK 0.2f
#define BNEPS 1e-5f
#define GNEPS 1e-5f

typedef short short8 __attribute__((ext_vector_type(8)));
typedef float float4_ __attribute__((ext_vector_type(4)));

__device__ __forceinline__ short f2bf(float f){
  unsigned u = __float_as_uint(f);
  u += 0x7FFF + ((u>>16)&1);          // RNE
  return (short)(u>>16);
}
__device__ __forceinline__ float bf2f(short s){
  unsigned u = ((unsigned)(unsigned short)s)<<16;
  return __uint_as_float(u);
}

// ---------------- voxelize stats ----------------
__global__ void k_voxstats(const float* __restrict__ coords, float* __restrict__ ms){
  int b = blockIdx.x;
  __shared__ float red[256];
  float mean[3];
  for(int d=0; d<3; d++){
    float s=0.f;
    for(int i=threadIdx.x; i<NP; i+=256) s += coords[(b*3+d)*NP+i];
    red[threadIdx.x]=s; __syncthreads();
    for(int o=128;o>0;o>>=1){ if(threadIdx.x<o) red[threadIdx.x]+=red[threadIdx.x+o]; __syncthreads(); }
    mean[d]=red[0]/(float)NP; __syncthreads();
  }
  float mx=0.f;
  for(int i=threadIdx.x; i<NP; i+=256){
    float x=coords[(b*3+0)*NP+i]-mean[0];
    float y=coords[(b*3+1)*NP+i]-mean[1];
    float z=coords[(b*3+2)*NP+i]-mean[2];
    mx=fmaxf(mx, sqrtf(x*x+y*y+z*z));
  }
  red[threadIdx.x]=mx; __syncthreads();
  for(int o=128;o>0;o>>=1){ if(threadIdx.x<o) red[threadIdx.x]=fmaxf(red[threadIdx.x],red[threadIdx.x+o]); __syncthreads(); }
  if(threadIdx.x==0){
    ms[b*4+0]=mean[0]; ms[b*4+1]=mean[1]; ms[b*4+2]=mean[2];
    ms[b*4+3]=red[0]*2.0f;
  }
}

// ---------------- norm coords + voxel index ----------------
__global__ void k_assign(const float* __restrict__ coords, const float* __restrict__ ms,
                         float* __restrict__ nc, int* __restrict__ vi){
  int t = blockIdx.x*256+threadIdx.x;
  if(t>=BB*NP) return;
  int b=t/NP, n=t-b*NP;
  float scale=ms[b*4+3];
  int vox[3];
  #pragma unroll
  for(int d=0; d<3; d++){
    float c=coords[(b*3+d)*NP+n] - ms[b*4+d];
    float v=(c/scale + 0.5f)*32.0f;
    v=fminf(fmaxf(v,0.0f),31.0f);
    nc[(b*3+d)*NP+n]=v;
    vox[d]=(int)rintf(v);
  }
  vi[t]=vox[0]*1024+vox[1]*32+vox[2];
}

// --------- scatter: one wave per point, lane = channel ----------
__global__ void k_scatter(const float* __restrict__ feat, const int* __restrict__ vi,
                          float* __restrict__ gsum, float* __restrict__ cnt){
  int wid = (blockIdx.x*256+threadIdx.x)>>6;
  int lane = threadIdx.x&63;
  if(wid>=BB*NP) return;
  int b=wid>>12, n=wid&4095;
  int idx=vi[wid];
  float f = feat[((size_t)(b*CH+lane))*NP + n];
  atomicAdd(gsum + ((size_t)b*R3+idx)*CH + lane, f);
  if(lane==0) atomicAdd(&cnt[b*R3+idx], 1.0f);
}

// ---------------- sums -> means, f32 -> bf16 grid ----------------
__global__ void k_gridmean(const float* __restrict__ gsum, const float* __restrict__ cnt,
                           short* __restrict__ gbf){
  int t=blockIdx.x*256+threadIdx.x;
  if(t>=BB*R3*8) return;
  int v=t>>3, q=t&7;
  float inv=1.0f/fmaxf(cnt[v],1.0f);
  const float* sp=gsum + (size_t)v*CH + q*8;
  short8 o;
  #pragma unroll
  for(int j=0;j<8;j++) o[j]=f2bf(sp[j]*inv);
  ((short8*)gbf)[(size_t)v*8+q]=o;
}

// ------- weights: w[oc][ci][tap] -> per-fragment contiguous bf16 -------
// frag = (tap*2+hh)*4+nf ; within frag: lane l, j -> W[nf*16+(l&15)][hh*32+(l>>4)*8+j]
__global__ void k_wt3(const float* __restrict__ w, short* __restrict__ wt3){
  int t=blockIdx.x*256+threadIdx.x;
  if(t>=CH*CH*27) return;
  int frag=t>>9, l=(t>>3)&63, j=t&7;
  int tap=frag>>3, hh=(frag>>2)&1, nf=frag&3;
  int oc=nf*16+(l&15);
  int ci=hh*32+(l>>4)*8+j;
  wt3[t]=f2bf(w[oc*1728 + ci*27 + tap]);
}

// ------------- MFMA implicit-GEMM 3x3x3 conv + bias + BN + leaky -------------
// tile 4z x 8y x 8x, 4 waves (wave = z-layer, M=64 rows), ci in 2 halves
__global__ __launch_bounds__(256,3) void k_conv_mfma(
    const short* __restrict__ gin, short* __restrict__ gout,
    const short* __restrict__ wt3, const float* __restrict__ bias,
    const float* __restrict__ bg, const float* __restrict__ bb,
    const float* __restrict__ bm, const float* __restrict__ bv){
  __shared__ __align__(16) short in_s[4*601*8];   // 38464 B
  int tid=threadIdx.x;
  int blk=blockIdx.x;                 // 8b x 8zt x 4yt x 4xt
  int b=blk>>7, zt=(blk>>4)&7, yt=(blk>>2)&3, xt=blk&3;
  int z0=zt*4, y0=yt*8, x0=xt*8;
  const short* gbase = gin + (size_t)b*R3*CH;

  int lane=tid&63, zl=tid>>6;
  int r15=lane&15, g=lane>>4;
  int ix=r15&7, iyq=r15>>3;

  float4_ acc[4][4];
  #pragma unroll
  for(int mf=0;mf<4;mf++)
    #pragma unroll
    for(int nf=0;nf<4;nf++) acc[mf][nf]=(float4_){0.f,0.f,0.f,0.f};

  short8* s8=(short8*)in_s;

  for(int hh=0; hh<2; hh++){
    __syncthreads();
    for(int e=tid; e<2400; e+=256){
      int ss=e>>2, cb=e&3;
      int z=ss/100, r2=ss-z*100, y=r2/10, x=r2-y*10;
      int gz=z0-1+z, gy=y0-1+y, gx=x0-1+x;
      short8 v={0,0,0,0,0,0,0,0};
      if(((unsigned)gz<32u)&&((unsigned)gy<32u)&&((unsigned)gx<32u))
        v=*(const short8*)(gbase + ((gz<<10)+(gy<<5)+gx)*CH + hh*32 + cb*8);
      s8[cb*601+ss]=v;
    }
    __syncthreads();

    // per-fragment contiguous B: base + tap*512 + nf*64 (+lane)
    const short8* wb = ((const short8*)wt3) + hh*256 + lane;
    short8 bw0[4], bw1[4];
    #pragma unroll
    for(int nf=0;nf<4;nf++) bw0[nf]=wb[nf*64];
    #pragma unroll
    for(int nf=0;nf<4;nf++) bw1[nf]=wb[512+nf*64];

    for(int tt=0; tt<27; tt+=2){
      {
        int kz=tt/9, r=tt-kz*9, ky=r/3, kx=r-ky*3;
        #pragma unroll
        for(int mf=0;mf<4;mf++){
          int ss=(zl+kz)*100+(mf*2+iyq+ky)*10+ix+kx;
          short8 a=s8[g*601+ss];
          #pragma unroll
          for(int nf=0;nf<4;nf++)
            acc[mf][nf]=__builtin_amdgcn_mfma_f32_16x16x32_bf16(a,bw0[nf],acc[mf][nf],0,0,0);
        }
        if(tt+2<27){
          #pragma unroll
          for(int nf=0;nf<4;nf++) bw0[nf]=wb[(tt+2)*512+nf*64];
        }
      }
      if(tt+1<27){
        int t1=tt+1;
        int kz=t1/9, r=t1-kz*9, ky=r/3, kx=r-ky*3;
        #pragma unroll
        for(int mf=0;mf<4;mf++){
          int ss=(zl+kz)*100+(mf*2+iyq+ky)*10+ix+kx;
          short8 a=s8[g*601+ss];
          #pragma unroll
          for(int nf=0;nf<4;nf++)
            acc[mf][nf]=__builtin_amdgcn_mfma_f32_16x16x32_bf16(a,bw1[nf],acc[mf][nf],0,0,0);
        }
        if(tt+3<27){
          #pragma unroll
          for(int nf=0;nf<4;nf++) bw1[nf]=wb[(tt+3)*512+nf*64];
        }
      }
    }
  }

  // ---- epilogue: bias + BN + leaky, bf16 out [vox][oc] ----
  short* go = gout + ((size_t)b*R3 + (size_t)(z0+zl)*1024)*CH;
  #pragma unroll
  for(int nf=0;nf<4;nf++){
    int oc=nf*16+r15;
    float iv=bg[oc]/sqrtf(bv[oc]+BNEPS);
    float sh=bias[oc]*iv + bb[oc]-bm[oc]*iv;
    #pragma unroll
    for(int mf=0;mf<4;mf++){
      #pragma unroll
      for(int q=0;q<4;q++){
        int row=mf*16+g*4+q;
        float val=acc[mf][nf][q]*iv+sh;
        val = val>=0.f ? val : LEAK*val;
        go[(size_t)((y0+(row>>3))*32 + x0+(row&7))*CH + oc]=f2bf(val);
      }
    }
  }
}

// ---------------- point MLP: y = W @ feat + b ----------------
__global__ void k_ptgemm(const float* __restrict__ feat, const float* __restrict__ w,
                         const float* __restrict__ bias, float* __restrict__ y){
  __shared__ float ws_[64*64];
  int tid=threadIdx.x;
  for(int e=tid;e<4096;e+=256) ws_[e]=w[e];
  __syncthreads();
  int t=blockIdx.x*256+tid;
  if(t>=BB*NP) return;
  int b=t/NP, n=t-b*NP;
  float f[64];
  #pragma unroll 8
  for(int c=0;c<64;c++) f[c]=feat[(size_t)(b*CH+c)*NP+n];
  for(int o=0;o<64;o++){
    float sAcc=bias[o];
    #pragma unroll 8
    for(int c=0;c<64;c++) sAcc=fmaf(f[c], ws_[o*64+c], sAcc);
    y[(size_t)(b*CH+o)*NP+n]=sAcc;
  }
}

// ---------------- GroupNorm stats ----------------
__global__ void k_gnstats(const float* __restrict__ py, float* __restrict__ st){
  int b=blockIdx.x>>3, g=blockIdx.x&7;
  __shared__ float rs[256], rq[256];
  float s=0.f,q=0.f;
  for(int i=threadIdx.x;i<8*NP;i+=256){
    int cc=i>>12, n=i&4095;
    float v=py[(size_t)(b*CH+g*8+cc)*NP+n];
    s+=v; q+=v*v;
  }
  rs[threadIdx.x]=s; rq[threadIdx.x]=q;
  __syncthreads();
  for(int o=128;o>0;o>>=1){
    if(threadIdx.x<o){ rs[threadIdx.x]+=rs[threadIdx.x+o]; rq[threadIdx.x]+=rq[threadIdx.x+o]; }
    __syncthreads();
  }
  if(threadIdx.x==0){
    float mu=rs[0]/(8.f*NP);
    float var=rq[0]/(8.f*NP)-mu*mu;
    st[blockIdx.x*2+0]=mu;
    st[blockIdx.x*2+1]=1.0f/sqrtf(var+GNEPS);
  }
}

// ------- devoxelize + GN affine + swish + add; LDS-transposed coalesced out -------
// block = 64 points x 4 thr (16 ch each); grid = 512
__global__ void k_fuse(const short* __restrict__ grid, const float* __restrict__ nc,
                       const float* __restrict__ py, const float* __restrict__ st,
                       const float* __restrict__ gg, const float* __restrict__ gb,
                       float* __restrict__ out){
  __shared__ float ot[64][65];
  int tid=threadIdx.x;
  int blk=blockIdx.x;
  int b=blk>>6, n0=(blk&63)*64;
  int nl=tid>>2, qq=tid&3;
  int n=n0+nl;

  float d_[3]; int i0[3], i1[3];
  #pragma unroll
  for(int dd=0;dd<3;dd++){
    float c=nc[(b*3+dd)*NP+n];
    c=fminf(fmaxf(c,0.f),31.f);
    float f=floorf(c);
    d_[dd]=c-f;
    i0[dd]=(int)f;
    i1[dd]=min(i0[dd]+1,31);
  }
  int idx8[8]; float w8[8];
  #pragma unroll
  for(int k=0;k<8;k++){
    int xx=(k&4)?i1[0]:i0[0];
    int yy=(k&2)?i1[1]:i0[1];
    int zz=(k&1)?i1[2]:i0[2];
    float wx=(k&4)?d_[0]:(1.f-d_[0]);
    float wy=(k&2)?d_[1]:(1.f-d_[1]);
    float wz=(k&1)?d_[2]:(1.f-d_[2]);
    idx8[k]=xx*1024+yy*32+zz;
    w8[k]=wx*wy*wz;
  }
  const short* gbase = grid + (size_t)b*R3*CH;
  #pragma unroll
  for(int c8=0;c8<2;c8++){
    int c0=qq*16+c8*8;
    float dv[8]={0.f,0.f,0.f,0.f,0.f,0.f,0.f,0.f};
    #pragma unroll
    for(int k=0;k<8;k++){
      short8 gv=*(const short8*)(gbase + (size_t)idx8[k]*CH + c0);
      #pragma unroll
      for(int j=0;j<8;j++) dv[j]+=w8[k]*bf2f(gv[j]);
    }
    #pragma unroll
    for(int j=0;j<8;j++){
      int c=c0+j;
      float mu  =st[(b*8+(c>>3))*2+0];
      float rstd=st[(b*8+(c>>3))*2+1];
      float yn=(py[(size_t)(b*CH+c)*NP+n]-mu)*rstd*gg[c]+gb[c];
      float sw=yn/(1.f+expf(-yn));
      ot[c][nl]=dv[j]+sw;
    }
  }
  __syncthreads();
  for(int i=tid;i<1024;i+=256){
    int c=i>>4, sg=i&15;
    float4_ v={ot[c][sg*4+0],ot[c][sg*4+1],ot[c][sg*4+2],ot[c][sg*4+3]};
    *(float4_*)(out + (size_t)(b*CH+c)*NP + n0 + sg*4) = v;
  }
}

// ---------------- passthrough copy ----------------
__global__ void k_copy(const float* __restrict__ src, float* __restrict__ dst, int n){
  int t=blockIdx.x*256+threadIdx.x;
  if(t<n) dst[t]=src[t];
}

extern "C" void kernel_launch(void* const* d_in, const int* in_sizes, int n_in,
                              void* d_out, int out_size, void* d_ws, size_t ws_size,
                              hipStream_t stream){
  const float* features=(const float*)d_in[0];
  const float* coords  =(const float*)d_in[1];
  const float* temb    =(const float*)d_in[2];
  const float* c1w=(const float*)d_in[3];
  const float* c1b=(const float*)d_in[4];
  const float* b1g=(const float*)d_in[5];
  const float* b1b=(const float*)d_in[6];
  const float* b1m=(const float*)d_in[7];
  const float* b1v=(const float*)d_in[8];
  const float* c2w=(const float*)d_in[9];
  const float* c2b=(const float*)d_in[10];
  const float* b2g=(const float*)d_in[11];
  const float* b2b=(const float*)d_in[12];
  const float* b2m=(const float*)d_in[13];
  const float* b2v=(const float*)d_in[14];
  const float* pfw=(const float*)d_in[15];
  const float* pfb=(const float*)d_in[16];
  const float* gng=(const float*)d_in[17];
  const float* gnb=(const float*)d_in[18];

  float* F=(float*)d_ws;
  float* ms  = F + 0;                   // 32
  float* nc  = F + 32;                  // 98304
  int*   vi  = (int*)(F + 98336);       // 32768
  short* w1t = (short*)(F + 131104);    // 110592 sh = 55296 f
  short* w2t = (short*)(F + 186400);    // 55296 f
  float* py  = F + 241696;              // 2097152
  float* st  = F + 2338848;             // 128
  float* cnt = F + 2338976;             // 262144
  float* gA  = F + 2601120;             // 16777216  (contiguous after cnt)
  short* gBF1= (short*)(F + 19378336);  // 8388608 f
  short* gBF2= (short*)(F + 27766944);  // 8388608 f
  float* out=(float*)d_out;

  hipMemsetAsync(cnt, 0, (size_t)(262144+16777216)*4, stream);

  k_voxstats<<<8,256,0,stream>>>(coords, ms);
  k_assign  <<<128,256,0,stream>>>(coords, ms, nc, vi);
  k_scatter <<<8192,256,0,stream>>>(features, vi, gA, cnt);
  k_gridmean<<<8192,256,0,stream>>>(gA, cnt, gBF1);
  k_wt3     <<<432,256,0,stream>>>(c1w, w1t);
  k_wt3     <<<432,256,0,stream>>>(c2w, w2t);
  k_conv_mfma<<<1024,256,0,stream>>>(gBF1, gBF2, w1t, c1b, b1g, b1b, b1m, b1v);
  k_conv_mfma<<<1024,256,0,stream>>>(gBF2, gBF1, w2t, c2b, b2g, b2b, b2m, b2v);
  k_ptgemm  <<<128,256,0,stream>>>(features, pfw, pfb, py);
  k_gnstats <<<64,256,0,stream>>>(py, st);
  k_fuse    <<<512,256,0,stream>>>(gBF1, nc, py, st, gng, gnb, out);
  k_copy    <<<(98304+255)/256,256,0,stream>>>(coords, out+2097152, 98304);
  k_copy    <<<2,256,0,stream>>>(temb, out+2195456, 512);
}

// Round 6
// 244.669 us; speedup vs baseline: 7.4715x; 1.4671x over previous
//
#include <hip/hip_runtime.h>
#include <hip/hip_bf16.h>
#include <math.h>

#define BB 8
#define CH 64
#define NP 4096
#define RG 32
#define R3 32768
#define LEAK 0.2f
#define BNEPS 1e-5f
#define GNEPS 1e-5f

typedef short short8 __attribute__((ext_vector_type(8)));
typedef float float4_ __attribute__((ext_vector_type(4)));

__device__ __forceinline__ short f2bf(float f){
  unsigned u = __float_as_uint(f);
  u += 0x7FFF + ((u>>16)&1);          // RNE
  return (short)(u>>16);
}
__device__ __forceinline__ float bf2f(short s){
  unsigned u = ((unsigned)(unsigned short)s)<<16;
  return __uint_as_float(u);
}

// ---------------- voxelize stats ----------------
__global__ void k_voxstats(const float* __restrict__ coords, float* __restrict__ ms){
  int b = blockIdx.x;
  __shared__ float red[256];
  float mean[3];
  for(int d=0; d<3; d++){
    float s=0.f;
    for(int i=threadIdx.x; i<NP; i+=256) s += coords[(b*3+d)*NP+i];
    red[threadIdx.x]=s; __syncthreads();
    for(int o=128;o>0;o>>=1){ if(threadIdx.x<o) red[threadIdx.x]+=red[threadIdx.x+o]; __syncthreads(); }
    mean[d]=red[0]/(float)NP; __syncthreads();
  }
  float mx=0.f;
  for(int i=threadIdx.x; i<NP; i+=256){
    float x=coords[(b*3+0)*NP+i]-mean[0];
    float y=coords[(b*3+1)*NP+i]-mean[1];
    float z=coords[(b*3+2)*NP+i]-mean[2];
    mx=fmaxf(mx, sqrtf(x*x+y*y+z*z));
  }
  red[threadIdx.x]=mx; __syncthreads();
  for(int o=128;o>0;o>>=1){ if(threadIdx.x<o) red[threadIdx.x]=fmaxf(red[threadIdx.x],red[threadIdx.x+o]); __syncthreads(); }
  if(threadIdx.x==0){
    ms[b*4+0]=mean[0]; ms[b*4+1]=mean[1]; ms[b*4+2]=mean[2];
    ms[b*4+3]=red[0]*2.0f;
  }
}

// ---------------- norm coords + voxel index ----------------
__global__ void k_assign(const float* __restrict__ coords, const float* __restrict__ ms,
                         float* __restrict__ nc, int* __restrict__ vi){
  int t = blockIdx.x*256+threadIdx.x;
  if(t>=BB*NP) return;
  int b=t/NP, n=t-b*NP;
  float scale=ms[b*4+3];
  int vox[3];
  #pragma unroll
  for(int d=0; d<3; d++){
    float c=coords[(b*3+d)*NP+n] - ms[b*4+d];
    float v=(c/scale + 0.5f)*32.0f;
    v=fminf(fmaxf(v,0.0f),31.0f);
    nc[(b*3+d)*NP+n]=v;
    vox[d]=(int)rintf(v);
  }
  vi[t]=vox[0]*1024+vox[1]*32+vox[2];
}

// --------- scatter: one wave per point, lane = channel ----------
__global__ void k_scatter(const float* __restrict__ feat, const int* __restrict__ vi,
                          float* __restrict__ gsum, float* __restrict__ cnt){
  int wid = (blockIdx.x*256+threadIdx.x)>>6;
  int lane = threadIdx.x&63;
  if(wid>=BB*NP) return;
  int b=wid>>12, n=wid&4095;
  int idx=vi[wid];
  float f = feat[((size_t)(b*CH+lane))*NP + n];
  atomicAdd(gsum + ((size_t)b*R3+idx)*CH + lane, f);
  if(lane==0) atomicAdd(&cnt[b*R3+idx], 1.0f);
}

// ---------------- sums -> means, f32 -> bf16 grid ----------------
__global__ void k_gridmean(const float* __restrict__ gsum, const float* __restrict__ cnt,
                           short* __restrict__ gbf){
  int t=blockIdx.x*256+threadIdx.x;
  if(t>=BB*R3*8) return;
  int v=t>>3, q=t&7;
  float inv=1.0f/fmaxf(cnt[v],1.0f);
  const float* sp=gsum + (size_t)v*CH + q*8;
  short8 o;
  #pragma unroll
  for(int j=0;j<8;j++) o[j]=f2bf(sp[j]*inv);
  ((short8*)gbf)[(size_t)v*8+q]=o;
}

// ------- weights: w[oc][ci][tap] -> per-fragment contiguous bf16 -------
__global__ void k_wt3(const float* __restrict__ w, short* __restrict__ wt3){
  int t=blockIdx.x*256+threadIdx.x;
  if(t>=CH*CH*27) return;
  int frag=t>>9, l=(t>>3)&63, j=t&7;
  int tap=frag>>3, hh=(frag>>2)&1, nf=frag&3;
  int oc=nf*16+(l&15);
  int ci=hh*32+(l>>4)*8+j;
  wt3[t]=f2bf(w[oc*1728 + ci*27 + tap]);
}

// ------------- MFMA implicit-GEMM 3x3x3 conv + bias + BN + leaky -------------
__global__ __launch_bounds__(256,3) void k_conv_mfma(
    const short* __restrict__ gin, short* __restrict__ gout,
    const short* __restrict__ wt3, const float* __restrict__ bias,
    const float* __restrict__ bg, const float* __restrict__ bb,
    const float* __restrict__ bm, const float* __restrict__ bv){
  __shared__ __align__(16) short in_s[4*601*8];   // 38464 B
  int tid=threadIdx.x;
  int blk=blockIdx.x;                 // 8b x 8zt x 4yt x 4xt
  int b=blk>>7, zt=(blk>>4)&7, yt=(blk>>2)&3, xt=blk&3;
  int z0=zt*4, y0=yt*8, x0=xt*8;
  const short* gbase = gin + (size_t)b*R3*CH;

  int lane=tid&63, zl=tid>>6;
  int r15=lane&15, g=lane>>4;
  int ix=r15&7, iyq=r15>>3;

  float4_ acc[4][4];
  #pragma unroll
  for(int mf=0;mf<4;mf++)
    #pragma unroll
    for(int nf=0;nf<4;nf++) acc[mf][nf]=(float4_){0.f,0.f,0.f,0.f};

  short8* s8=(short8*)in_s;

  for(int hh=0; hh<2; hh++){
    __syncthreads();
    for(int e=tid; e<2400; e+=256){
      int ss=e>>2, cb=e&3;
      int z=ss/100, r2=ss-z*100, y=r2/10, x=r2-y*10;
      int gz=z0-1+z, gy=y0-1+y, gx=x0-1+x;
      short8 v={0,0,0,0,0,0,0,0};
      if(((unsigned)gz<32u)&&((unsigned)gy<32u)&&((unsigned)gx<32u))
        v=*(const short8*)(gbase + ((gz<<10)+(gy<<5)+gx)*CH + hh*32 + cb*8);
      s8[cb*601+ss]=v;
    }
    __syncthreads();

    const short8* wb = ((const short8*)wt3) + hh*256 + lane;
    short8 bw0[4], bw1[4];
    #pragma unroll
    for(int nf=0;nf<4;nf++) bw0[nf]=wb[nf*64];
    #pragma unroll
    for(int nf=0;nf<4;nf++) bw1[nf]=wb[512+nf*64];

    for(int tt=0; tt<27; tt+=2){
      {
        int kz=tt/9, r=tt-kz*9, ky=r/3, kx=r-ky*3;
        #pragma unroll
        for(int mf=0;mf<4;mf++){
          int ss=(zl+kz)*100+(mf*2+iyq+ky)*10+ix+kx;
          short8 a=s8[g*601+ss];
          #pragma unroll
          for(int nf=0;nf<4;nf++)
            acc[mf][nf]=__builtin_amdgcn_mfma_f32_16x16x32_bf16(a,bw0[nf],acc[mf][nf],0,0,0);
        }
        if(tt+2<27){
          #pragma unroll
          for(int nf=0;nf<4;nf++) bw0[nf]=wb[(tt+2)*512+nf*64];
        }
      }
      if(tt+1<27){
        int t1=tt+1;
        int kz=t1/9, r=t1-kz*9, ky=r/3, kx=r-ky*3;
        #pragma unroll
        for(int mf=0;mf<4;mf++){
          int ss=(zl+kz)*100+(mf*2+iyq+ky)*10+ix+kx;
          short8 a=s8[g*601+ss];
          #pragma unroll
          for(int nf=0;nf<4;nf++)
            acc[mf][nf]=__builtin_amdgcn_mfma_f32_16x16x32_bf16(a,bw1[nf],acc[mf][nf],0,0,0);
        }
        if(tt+3<27){
          #pragma unroll
          for(int nf=0;nf<4;nf++) bw1[nf]=wb[(tt+3)*512+nf*64];
        }
      }
    }
  }

  short* go = gout + ((size_t)b*R3 + (size_t)(z0+zl)*1024)*CH;
  #pragma unroll
  for(int nf=0;nf<4;nf++){
    int oc=nf*16+r15;
    float iv=bg[oc]/sqrtf(bv[oc]+BNEPS);
    float sh=bias[oc]*iv + bb[oc]-bm[oc]*iv;
    #pragma unroll
    for(int mf=0;mf<4;mf++){
      #pragma unroll
      for(int q=0;q<4;q++){
        int row=mf*16+g*4+q;
        float val=acc[mf][nf][q]*iv+sh;
        val = val>=0.f ? val : LEAK*val;
        go[(size_t)((y0+(row>>3))*32 + x0+(row&7))*CH + oc]=f2bf(val);
      }
    }
  }
}

// ------- point MLP + fused GN partial stats -------
// 512 blocks: b(8) x 64 point-chunks of 64; 4 thr/pt x 16 outs
__global__ __launch_bounds__(256,2) void k_ptgemm(
    const float* __restrict__ feat, const float* __restrict__ w,
    const float* __restrict__ bias, float* __restrict__ y,
    float* __restrict__ stp){
  __shared__ float ws_[64*64];
  __shared__ float ft[64][65];
  __shared__ float sg[8], qg[8];
  int tid=threadIdx.x;
  int blk=blockIdx.x;
  int b=blk>>6, n0=(blk&63)*64;
  for(int e=tid;e<4096;e+=256) ws_[e]=w[e];
  for(int e=tid;e<4096;e+=256){
    int c=e>>6, nl=e&63;
    ft[c][nl]=feat[(size_t)(b*CH+c)*NP + n0+nl];
  }
  if(tid<8){ sg[tid]=0.f; qg[tid]=0.f; }
  __syncthreads();
  int nl=tid&63, qq=tid>>6;
  float ps[2]={0.f,0.f}, pq[2]={0.f,0.f};
  #pragma unroll
  for(int j=0;j<16;j++){
    int o=qq*16+j;
    float a=bias[o];
    #pragma unroll
    for(int c=0;c<64;c++) a=fmaf(ws_[o*64+c], ft[c][nl], a);
    y[(size_t)(b*CH+o)*NP+n0+nl]=a;
    int gi=j>>3;
    ps[gi]+=a; pq[gi]+=a*a;
  }
  // wave-level reduce (all lanes same qq)
  #pragma unroll
  for(int off=32;off>0;off>>=1){
    ps[0]+=__shfl_down(ps[0],off,64); pq[0]+=__shfl_down(pq[0],off,64);
    ps[1]+=__shfl_down(ps[1],off,64); pq[1]+=__shfl_down(pq[1],off,64);
  }
  if((tid&63)==0){
    atomicAdd(&sg[qq*2+0],ps[0]); atomicAdd(&qg[qq*2+0],pq[0]);
    atomicAdd(&sg[qq*2+1],ps[1]); atomicAdd(&qg[qq*2+1],pq[1]);
  }
  __syncthreads();
  if(tid<8){
    atomicAdd(&stp[(b*8+tid)*2+0], sg[tid]);
    atomicAdd(&stp[(b*8+tid)*2+1], qg[tid]);
  }
}

// ---------------- finalize GN stats ----------------
__global__ void k_gnfinal(const float* __restrict__ stp, float* __restrict__ st){
  int t=threadIdx.x;
  if(t>=64) return;
  float s=stp[t*2+0], q=stp[t*2+1];
  float mu=s/(8.f*NP);
  float var=q/(8.f*NP)-mu*mu;
  st[t*2+0]=mu;
  st[t*2+1]=1.0f/sqrtf(var+GNEPS);
}

// ------- devoxelize + GN affine + swish + add; LDS-transposed coalesced out -------
__global__ void k_fuse(const short* __restrict__ grid, const float* __restrict__ nc,
                       const float* __restrict__ py, const float* __restrict__ st,
                       const float* __restrict__ gg, const float* __restrict__ gb,
                       float* __restrict__ out){
  __shared__ float ot[64][65];
  int tid=threadIdx.x;
  int blk=blockIdx.x;
  int b=blk>>6, n0=(blk&63)*64;
  int nl=tid>>2, qq=tid&3;
  int n=n0+nl;

  float d_[3]; int i0[3], i1[3];
  #pragma unroll
  for(int dd=0;dd<3;dd++){
    float c=nc[(b*3+dd)*NP+n];
    c=fminf(fmaxf(c,0.f),31.f);
    float f=floorf(c);
    d_[dd]=c-f;
    i0[dd]=(int)f;
    i1[dd]=min(i0[dd]+1,31);
  }
  int idx8[8]; float w8[8];
  #pragma unroll
  for(int k=0;k<8;k++){
    int xx=(k&4)?i1[0]:i0[0];
    int yy=(k&2)?i1[1]:i0[1];
    int zz=(k&1)?i1[2]:i0[2];
    float wx=(k&4)?d_[0]:(1.f-d_[0]);
    float wy=(k&2)?d_[1]:(1.f-d_[1]);
    float wz=(k&1)?d_[2]:(1.f-d_[2]);
    idx8[k]=xx*1024+yy*32+zz;
    w8[k]=wx*wy*wz;
  }
  const short* gbase = grid + (size_t)b*R3*CH;
  #pragma unroll
  for(int c8=0;c8<2;c8++){
    int c0=qq*16+c8*8;
    float dv[8]={0.f,0.f,0.f,0.f,0.f,0.f,0.f,0.f};
    #pragma unroll
    for(int k=0;k<8;k++){
      short8 gv=*(const short8*)(gbase + (size_t)idx8[k]*CH + c0);
      #pragma unroll
      for(int j=0;j<8;j++) dv[j]+=w8[k]*bf2f(gv[j]);
    }
    #pragma unroll
    for(int j=0;j<8;j++){
      int c=c0+j;
      float mu  =st[(b*8+(c>>3))*2+0];
      float rstd=st[(b*8+(c>>3))*2+1];
      float yn=(py[(size_t)(b*CH+c)*NP+n]-mu)*rstd*gg[c]+gb[c];
      float sw=yn/(1.f+expf(-yn));
      ot[c][nl]=dv[j]+sw;
    }
  }
  __syncthreads();
  for(int i=tid;i<1024;i+=256){
    int c=i>>4, sg=i&15;
    float4_ v={ot[c][sg*4+0],ot[c][sg*4+1],ot[c][sg*4+2],ot[c][sg*4+3]};
    *(float4_*)(out + (size_t)(b*CH+c)*NP + n0 + sg*4) = v;
  }
}

// ---------------- passthrough copy ----------------
__global__ void k_copy(const float* __restrict__ src, float* __restrict__ dst, int n){
  int t=blockIdx.x*256+threadIdx.x;
  if(t<n) dst[t]=src[t];
}

extern "C" void kernel_launch(void* const* d_in, const int* in_sizes, int n_in,
                              void* d_out, int out_size, void* d_ws, size_t ws_size,
                              hipStream_t stream){
  const float* features=(const float*)d_in[0];
  const float* coords  =(const float*)d_in[1];
  const float* temb    =(const float*)d_in[2];
  const float* c1w=(const float*)d_in[3];
  const float* c1b=(const float*)d_in[4];
  const float* b1g=(const float*)d_in[5];
  const float* b1b=(const float*)d_in[6];
  const float* b1m=(const float*)d_in[7];
  const float* b1v=(const float*)d_in[8];
  const float* c2w=(const float*)d_in[9];
  const float* c2b=(const float*)d_in[10];
  const float* b2g=(const float*)d_in[11];
  const float* b2b=(const float*)d_in[12];
  const float* b2m=(const float*)d_in[13];
  const float* b2v=(const float*)d_in[14];
  const float* pfw=(const float*)d_in[15];
  const float* pfb=(const float*)d_in[16];
  const float* gng=(const float*)d_in[17];
  const float* gnb=(const float*)d_in[18];

  float* F=(float*)d_ws;
  float* ms  = F + 0;                   // 32
  float* nc  = F + 32;                  // 98304
  int*   vi  = (int*)(F + 98336);       // 32768
  short* w1t = (short*)(F + 131104);    // 55296 f
  short* w2t = (short*)(F + 186400);    // 55296 f
  float* py  = F + 241696;              // 2097152
  float* st  = F + 2338848;             // 128
  float* stp = F + 2338976;             // 128  (memset from here)
  float* cnt = F + 2339104;             // 262144
  float* gA  = F + 2601248;             // 16777216
  short* gBF1= (short*)(F + 19378464);  // 8388608 f
  short* gBF2= (short*)(F + 27767072);  // 8388608 f
  float* out=(float*)d_out;

  hipMemsetAsync(stp, 0, (size_t)(128+262144+16777216)*4, stream);

  k_voxstats<<<8,256,0,stream>>>(coords, ms);
  k_assign  <<<128,256,0,stream>>>(coords, ms, nc, vi);
  k_scatter <<<8192,256,0,stream>>>(features, vi, gA, cnt);
  k_gridmean<<<8192,256,0,stream>>>(gA, cnt, gBF1);
  k_wt3     <<<432,256,0,stream>>>(c1w, w1t);
  k_wt3     <<<432,256,0,stream>>>(c2w, w2t);
  k_conv_mfma<<<1024,256,0,stream>>>(gBF1, gBF2, w1t, c1b, b1g, b1b, b1m, b1v);
  k_conv_mfma<<<1024,256,0,stream>>>(gBF2, gBF1, w2t, c2b, b2g, b2b, b2m, b2v);
  k_ptgemm  <<<512,256,0,stream>>>(features, pfw, pfb, py, stp);
  k_gnfinal <<<1,64,0,stream>>>(stp, st);
  k_fuse    <<<512,256,0,stream>>>(gBF1, nc, py, st, gng, gnb, out);
  k_copy    <<<(98304+255)/256,256,0,stream>>>(coords, out+2097152, 98304);
  k_copy    <<<2,256,0,stream>>>(temb, out+2195456, 512);
}